// Round 1
// baseline (606.631 us; speedup 1.0000x reference)
//
#include <hip/hip_runtime.h>

typedef unsigned short u16;
typedef unsigned int   u32;

#define BM 128
#define BN 128
#define BK 32

typedef __attribute__((ext_vector_type(8))) short bf16x8;
typedef __attribute__((ext_vector_type(4))) float f32x4;

// ---- fp32 -> bf16 (RNE) ----
__device__ __forceinline__ u16 f2bf(float f) {
    union { float f; u32 u; } v; v.f = f;
    u32 u = v.u;
    u32 r = (u + 0x7FFFu + ((u >> 16) & 1u)) >> 16;
    return (u16)r;
}

// x: fp32 -> bf16, 8 elements/thread, 16B stores
__global__ void cvt_x_kernel(const float4* __restrict__ x, uint4* __restrict__ o, int n8) {
    int i = blockIdx.x * blockDim.x + threadIdx.x;
    if (i >= n8) return;
    float4 a = x[2 * i], b = x[2 * i + 1];
    uint4 r;
    r.x = (u32)f2bf(a.x) | ((u32)f2bf(a.y) << 16);
    r.y = (u32)f2bf(a.z) | ((u32)f2bf(a.w) << 16);
    r.z = (u32)f2bf(b.x) | ((u32)f2bf(b.y) << 16);
    r.w = (u32)f2bf(b.z) | ((u32)f2bf(b.w) << 16);
    o[i] = r;
}

// sign(w): +1 -> 0x3F80, -1 -> 0xBF80, 0 -> 0 (exact in bf16)
__device__ __forceinline__ u32 sgnbf2(float a, float b) {
    u32 lo = (a > 0.f) ? 0x3F80u : ((a < 0.f) ? 0xBF80u : 0u);
    u32 hi = (b > 0.f) ? 0x3F80u : ((b < 0.f) ? 0xBF80u : 0u);
    return lo | (hi << 16);
}

__global__ void cvt_w_kernel(const float4* __restrict__ w, uint4* __restrict__ o, int n8) {
    int i = blockIdx.x * blockDim.x + threadIdx.x;
    if (i >= n8) return;
    float4 a = w[2 * i], b = w[2 * i + 1];
    uint4 r;
    r.x = sgnbf2(a.x, a.y);
    r.y = sgnbf2(a.z, a.w);
    r.z = sgnbf2(b.x, b.y);
    r.w = sgnbf2(b.z, b.w);
    o[i] = r;
}

// async 16B global -> LDS
__device__ __forceinline__ void async_cp16(const void* gp, void* lp) {
    __builtin_amdgcn_global_load_lds(
        (__attribute__((address_space(1))) void*)(gp),
        (__attribute__((address_space(3))) void*)(lp),
        16, 0, 0);
}

// C[M,N] = A[M,K](bf16) * B[N,K]^T(bf16 +-1) + bias ; C fp32
// m97 structure: 128x128 tile, BK=32, 4 waves 2x2, 4x4 of 16x16x32 MFMA per wave.
__global__ void __launch_bounds__(256) gemm_bf16_bt(
    const u16* __restrict__ A, const u16* __restrict__ B,
    const float* __restrict__ bias, float* __restrict__ C,
    int M, int N, int K)
{
    __shared__ u16 As[BM * BK];   // 8 KB, row-major [128][32], no padding (global_load_lds needs contiguity)
    __shared__ u16 Bs[BN * BK];   // 8 KB

    const int t    = threadIdx.x;      // 0..255
    const int lane = t & 63;
    const int wave = t >> 6;
    const int wm   = (wave & 1) * 64;  // wave 2x2 -> 64x64 per wave
    const int wn   = (wave >> 1) * 64;
    const int l15  = lane & 15;
    const int quad = lane >> 4;

    const int m_block = blockIdx.y * BM;
    const int n_block = blockIdx.x * BN;

    f32x4 acc[4][4];
#pragma unroll
    for (int i = 0; i < 4; ++i)
#pragma unroll
        for (int j = 0; j < 4; ++j)
            acc[i][j] = (f32x4){0.f, 0.f, 0.f, 0.f};

    // staging chunk indices: 512 x 16B chunks per 8KB tile; thread t covers chunks t and t+256
    const int li0 = t,       ar0 = li0 >> 2, ak0 = (li0 & 3) * 8;
    const int li1 = t + 256, ar1 = li1 >> 2, ak1 = (li1 & 3) * 8;

    const u16* Abase = A + (size_t)m_block * K;
    const u16* Bbase = B + (size_t)n_block * K;

    for (int kt = 0; kt < K; kt += BK) {
        __syncthreads();  // previous iter's ds_reads done before overwrite
        async_cp16(Abase + (size_t)ar0 * K + kt + ak0, &As[li0 * 8]);
        async_cp16(Abase + (size_t)ar1 * K + kt + ak1, &As[li1 * 8]);
        async_cp16(Bbase + (size_t)ar0 * K + kt + ak0, &Bs[li0 * 8]);
        async_cp16(Bbase + (size_t)ar1 * K + kt + ak1, &Bs[li1 * 8]);
        __syncthreads();  // vmcnt(0) drain: tiles resident

        bf16x8 af[4], bg[4];
#pragma unroll
        for (int i = 0; i < 4; ++i) {
            af[i] = *(const bf16x8*)&As[(wm + i * 16 + l15) * BK + quad * 8];
            bg[i] = *(const bf16x8*)&Bs[(wn + i * 16 + l15) * BK + quad * 8];
        }
#pragma unroll
        for (int i = 0; i < 4; ++i)
#pragma unroll
            for (int j = 0; j < 4; ++j)
                acc[i][j] = __builtin_amdgcn_mfma_f32_16x16x32_bf16(af[i], bg[j], acc[i][j], 0, 0, 0);
    }

    // epilogue: C/D layout col=lane&15, row=quad*4+reg (m89-verified)
#pragma unroll
    for (int j = 0; j < 4; ++j) {
        const int col = n_block + wn + j * 16 + l15;
        const float bv = bias[col];
#pragma unroll
        for (int i = 0; i < 4; ++i) {
            const int row0 = m_block + wm + i * 16 + quad * 4;
#pragma unroll
            for (int r = 0; r < 4; ++r)
                C[(size_t)(row0 + r) * N + col] = acc[i][j][r] + bv;
        }
    }
}

extern "C" void kernel_launch(void* const* d_in, const int* in_sizes, int n_in,
                              void* d_out, int out_size, void* d_ws, size_t ws_size,
                              hipStream_t stream) {
    const float* x  = (const float*)d_in[0];   // [M,K]
    const float* w  = (const float*)d_in[1];   // [N,K]
    const float* bs = (const float*)d_in[2];   // [N]
    float* out = (float*)d_out;                // [M,N]

    const int N = in_sizes[2];
    const int K = in_sizes[1] / N;
    const int M = in_sizes[0] / K;

    u16* xb = (u16*)d_ws;                       // bf16 x  [M,K]
    u16* wb = xb + (size_t)M * K;               // bf16 sign(w) [N,K]

    const int nx8 = (int)(((size_t)M * K) / 8);
    const int nw8 = (int)(((size_t)N * K) / 8);
    cvt_x_kernel<<<(nx8 + 255) / 256, 256, 0, stream>>>((const float4*)x, (uint4*)xb, nx8);
    cvt_w_kernel<<<(nw8 + 255) / 256, 256, 0, stream>>>((const float4*)w, (uint4*)wb, nw8);

    dim3 grid(N / BN, M / BM);  // (32, 64)
    gemm_bf16_bt<<<grid, 256, 0, stream>>>(xb, wb, bs, out, M, N, K);
}

// Round 2
// 559.049 us; speedup vs baseline: 1.0851x; 1.0851x over previous
//
#include <hip/hip_runtime.h>

typedef unsigned short u16;
typedef unsigned int   u32;

#define BM 128
#define BN 128
#define BK 32

typedef __attribute__((ext_vector_type(8))) short bf16x8;
typedef __attribute__((ext_vector_type(4))) float f32x4;
typedef __attribute__((ext_vector_type(4))) float f4v;
typedef __attribute__((ext_vector_type(4))) u32   u4v;

// ---- fp32 -> bf16 (RNE) ----
__device__ __forceinline__ u16 f2bf(float f) {
    union { float f; u32 u; } v; v.f = f;
    u32 u = v.u;
    u32 r = (u + 0x7FFFu + ((u >> 16) & 1u)) >> 16;
    return (u16)r;
}

// sign(w): +1 -> 0x3F80, -1 -> 0xBF80, 0 -> 0 (exact in bf16)
__device__ __forceinline__ u32 sgnbf2(float a, float b) {
    u32 lo = (a > 0.f) ? 0x3F80u : ((a < 0.f) ? 0xBF80u : 0u);
    u32 hi = (b > 0.f) ? 0x3F80u : ((b < 0.f) ? 0xBF80u : 0u);
    return lo | (hi << 16);
}

// Fused converter: one dispatch covers x (chunks [0,nx8)) and w (chunks [nx8,ntot8)).
// Chunk = 8 fp32 in (32B, nontemporal: single-use), 8 bf16 out (16B, cached: GEMM re-reads).
// nx8 is a multiple of 256, so the region branch is block-uniform (no divergence).
__global__ void __launch_bounds__(256) cvt_fused(
    const f4v* __restrict__ x, const f4v* __restrict__ w,
    u4v* __restrict__ xb, u4v* __restrict__ wb, int nx8, int ntot8)
{
    int i = blockIdx.x * blockDim.x + threadIdx.x;
    if (i >= ntot8) return;
    if (i < nx8) {
        f4v a = __builtin_nontemporal_load(&x[2 * i]);
        f4v b = __builtin_nontemporal_load(&x[2 * i + 1]);
        u4v r;
        r.x = (u32)f2bf(a.x) | ((u32)f2bf(a.y) << 16);
        r.y = (u32)f2bf(a.z) | ((u32)f2bf(a.w) << 16);
        r.z = (u32)f2bf(b.x) | ((u32)f2bf(b.y) << 16);
        r.w = (u32)f2bf(b.z) | ((u32)f2bf(b.w) << 16);
        xb[i] = r;
    } else {
        int j = i - nx8;
        f4v a = __builtin_nontemporal_load(&w[2 * j]);
        f4v b = __builtin_nontemporal_load(&w[2 * j + 1]);
        u4v r;
        r.x = sgnbf2(a.x, a.y);
        r.y = sgnbf2(a.z, a.w);
        r.z = sgnbf2(b.x, b.y);
        r.w = sgnbf2(b.z, b.w);
        wb[j] = r;
    }
}

// async 16B global -> LDS
__device__ __forceinline__ void async_cp16(const void* gp, void* lp) {
    __builtin_amdgcn_global_load_lds(
        (__attribute__((address_space(1))) void*)(gp),
        (__attribute__((address_space(3))) void*)(lp),
        16, 0, 0);
}

// C[M,N] = A[M,K](bf16) * B[N,K]^T(bf16 +-1) + bias ; C fp32
// m97 structure: 128x128 tile, BK=32, 4 waves 2x2, 4x4 of 16x16x32 MFMA per wave.
// 1D grid + XCD-aware decode: bid%8 = XCD (HW round-robin); each XCD gets a
// 16x16 block patch, Morton-ordered in 8x8 subpatches, to bound the concurrent
// A/B working set per 4MB XCD-private L2.
__global__ void __launch_bounds__(256) gemm_bf16_bt(
    const u16* __restrict__ A, const u16* __restrict__ B,
    const float* __restrict__ bias, float* __restrict__ C,
    int M, int N, int K)
{
    __shared__ u16 As[BM * BK];   // 8 KB, row-major [128][32], no padding (global_load_lds needs contiguity)
    __shared__ u16 Bs[BN * BK];   // 8 KB

    const int t    = threadIdx.x;      // 0..255
    const int lane = t & 63;
    const int wave = t >> 6;
    const int wm   = (wave & 1) * 64;  // wave 2x2 -> 64x64 per wave
    const int wn   = (wave >> 1) * 64;
    const int l15  = lane & 15;
    const int quad = lane >> 4;

    const int nbm = M / BM, nbn = N / BN;
    int mb, nb;
    const int bid = blockIdx.x;
    if (nbm == 64 && nbn == 32) {
        const int xcd    = bid & 7;        // HW assigns block i -> XCD i%8
        const int local  = bid >> 3;       // 0..255 within XCD
        const int sub    = local >> 6;     // 2x2 of 8x8 subpatches
        const int within = local & 63;
        mb = ((xcd >> 1) << 4) + ((sub >> 1) << 3) + (within >> 3);
        nb = ((xcd & 1) << 4) + ((sub & 1) << 3) + (within & 7);
    } else {
        mb = bid / nbn;
        nb = bid - mb * nbn;
    }
    const int m_block = mb * BM;
    const int n_block = nb * BN;

    f32x4 acc[4][4];
#pragma unroll
    for (int i = 0; i < 4; ++i)
#pragma unroll
        for (int j = 0; j < 4; ++j)
            acc[i][j] = (f32x4){0.f, 0.f, 0.f, 0.f};

    // staging chunk indices: 512 x 16B chunks per 8KB tile; thread t covers chunks t and t+256
    const int li0 = t,       ar0 = li0 >> 2, ak0 = (li0 & 3) * 8;
    const int li1 = t + 256, ar1 = li1 >> 2, ak1 = (li1 & 3) * 8;

    const u16* Abase = A + (size_t)m_block * K;
    const u16* Bbase = B + (size_t)n_block * K;

    for (int kt = 0; kt < K; kt += BK) {
        __syncthreads();  // previous iter's ds_reads done before overwrite
        async_cp16(Abase + (size_t)ar0 * K + kt + ak0, &As[li0 * 8]);
        async_cp16(Abase + (size_t)ar1 * K + kt + ak1, &As[li1 * 8]);
        async_cp16(Bbase + (size_t)ar0 * K + kt + ak0, &Bs[li0 * 8]);
        async_cp16(Bbase + (size_t)ar1 * K + kt + ak1, &Bs[li1 * 8]);
        __syncthreads();  // vmcnt(0) drain: tiles resident

        bf16x8 af[4], bg[4];
#pragma unroll
        for (int i = 0; i < 4; ++i) {
            af[i] = *(const bf16x8*)&As[(wm + i * 16 + l15) * BK + quad * 8];
            bg[i] = *(const bf16x8*)&Bs[(wn + i * 16 + l15) * BK + quad * 8];
        }
#pragma unroll
        for (int i = 0; i < 4; ++i)
#pragma unroll
            for (int j = 0; j < 4; ++j)
                acc[i][j] = __builtin_amdgcn_mfma_f32_16x16x32_bf16(af[i], bg[j], acc[i][j], 0, 0, 0);
    }

    // epilogue: C/D layout col=lane&15, row=quad*4+reg (m89-verified)
    // nontemporal stores: C is 135MB write-once -> keep it out of the L2 that
    // A/B tiles need.
#pragma unroll
    for (int j = 0; j < 4; ++j) {
        const int col = n_block + wn + j * 16 + l15;
        const float bv = bias[col];
#pragma unroll
        for (int i = 0; i < 4; ++i) {
            const int row0 = m_block + wm + i * 16 + quad * 4;
#pragma unroll
            for (int r = 0; r < 4; ++r)
                __builtin_nontemporal_store(acc[i][j][r] + bv,
                                            &C[(size_t)(row0 + r) * N + col]);
        }
    }
}

extern "C" void kernel_launch(void* const* d_in, const int* in_sizes, int n_in,
                              void* d_out, int out_size, void* d_ws, size_t ws_size,
                              hipStream_t stream) {
    const float* x  = (const float*)d_in[0];   // [M,K]
    const float* w  = (const float*)d_in[1];   // [N,K]
    const float* bs = (const float*)d_in[2];   // [N]
    float* out = (float*)d_out;                // [M,N]

    const int N = in_sizes[2];
    const int K = in_sizes[1] / N;
    const int M = in_sizes[0] / K;

    u16* xb = (u16*)d_ws;                       // bf16 x  [M,K]
    u16* wb = xb + (size_t)M * K;               // bf16 sign(w) [N,K]

    const int nx8   = (int)(((size_t)M * K) / 8);
    const int nw8   = (int)(((size_t)N * K) / 8);
    const int ntot8 = nx8 + nw8;
    cvt_fused<<<(ntot8 + 255) / 256, 256, 0, stream>>>(
        (const f4v*)x, (const f4v*)w, (u4v*)xb, (u4v*)wb, nx8, ntot8);

    const int nblocks = (M / BM) * (N / BN);   // 2048
    gemm_bf16_bt<<<nblocks, 256, 0, stream>>>(xb, wb, bs, out, M, N, K);
}

// Round 3
// 430.540 us; speedup vs baseline: 1.4090x; 1.2985x over previous
//
#include <hip/hip_runtime.h>

typedef unsigned short u16;
typedef unsigned int   u32;
typedef signed char    i8;

#define BM 128
#define BN 128
#define BK 64

typedef __attribute__((ext_vector_type(4))) int   i32x4;
typedef __attribute__((ext_vector_type(4))) float f4v;
typedef __attribute__((ext_vector_type(4))) u32   u4v;

// ============================================================
// Fused quantizer, one dispatch:
//   blocks [0, xblocks)      : per-row int8 quantization of x with per-row
//                              scale s[row] = absmax/127 (symmetric).
//   blocks [xblocks, total)  : sign(w) -> int8 in {-1,0,+1}.
// Both branches are block-uniform. NT loads: fp32 sources are single-use.
// ============================================================
__global__ void __launch_bounds__(256) quant_fused(
    const f4v* __restrict__ x, const f4v* __restrict__ w,
    i8* __restrict__ xq, i8* __restrict__ wq, float* __restrict__ s,
    int K, int xblocks)
{
    const int t    = threadIdx.x;
    const int lane = t & 63;
    const int wave = t >> 6;

    if ((int)blockIdx.x < xblocks) {
        // ---- one block per row of x; K/4 float4s per row (K=4096 -> 1024) ----
        const int row = blockIdx.x;
        const f4v* xr = x + (size_t)row * (K >> 2);
        f4v v[4];
        float amax = 0.f;
#pragma unroll
        for (int c = 0; c < 4; ++c) {
            v[c] = __builtin_nontemporal_load(&xr[t + c * 256]);
            amax = fmaxf(amax, fmaxf(fmaxf(fabsf(v[c].x), fabsf(v[c].y)),
                                     fmaxf(fabsf(v[c].z), fabsf(v[c].w))));
        }
        // wave reduce (64 lanes) then cross-wave via LDS
#pragma unroll
        for (int off = 32; off > 0; off >>= 1)
            amax = fmaxf(amax, __shfl_down(amax, off));
        __shared__ float red[4];
        if (lane == 0) red[wave] = amax;
        __syncthreads();
        amax = fmaxf(fmaxf(red[0], red[1]), fmaxf(red[2], red[3]));

        const float inv = (amax > 0.f) ? (127.0f / amax) : 0.f;
        if (t == 0) s[row] = amax * (1.0f / 127.0f);

        i8* xo = xq + (size_t)row * K;
#pragma unroll
        for (int c = 0; c < 4; ++c) {
            const int e = (t + c * 256) * 4;       // element offset in row
            int q0 = __float2int_rn(v[c].x * inv);
            int q1 = __float2int_rn(v[c].y * inv);
            int q2 = __float2int_rn(v[c].z * inv);
            int q3 = __float2int_rn(v[c].w * inv);
            u32 p = (q0 & 0xFF) | ((q1 & 0xFF) << 8) |
                    ((q2 & 0xFF) << 16) | ((u32)(q3 & 0xFF) << 24);
            *(u32*)&xo[e] = p;
        }
    } else {
        // ---- w sign pack: 16 floats -> 16 int8 per thread ----
        const int b = blockIdx.x - xblocks;
        const size_t e0 = ((size_t)b * 256 + t) * 16; // element index
        const f4v* wp = w + (e0 >> 2);
        u32 pk[4];
#pragma unroll
        for (int c = 0; c < 4; ++c) {
            f4v a = __builtin_nontemporal_load(&wp[c]);
            u32 b0 = (a.x > 0.f) ? 1u : ((a.x < 0.f) ? 0xFFu : 0u);
            u32 b1 = (a.y > 0.f) ? 1u : ((a.y < 0.f) ? 0xFFu : 0u);
            u32 b2 = (a.z > 0.f) ? 1u : ((a.z < 0.f) ? 0xFFu : 0u);
            u32 b3 = (a.w > 0.f) ? 1u : ((a.w < 0.f) ? 0xFFu : 0u);
            pk[c] = b0 | (b1 << 8) | (b2 << 16) | (b3 << 24);
        }
        u4v r; r.x = pk[0]; r.y = pk[1]; r.z = pk[2]; r.w = pk[3];
        *(u4v*)&wq[e0] = r;
    }
}

// async 16B global -> LDS (wave-uniform LDS base + lane*16)
__device__ __forceinline__ void async_cp16(const void* gp, void* lp) {
    __builtin_amdgcn_global_load_lds(
        (__attribute__((address_space(1))) void*)(gp),
        (__attribute__((address_space(3))) void*)(lp),
        16, 0, 0);
}

// ============================================================
// C[M,N] = (xq[M,K] . wq[N,K]^T) * s[row] + bias[col]   (i8 MFMA, i32 acc)
// m97 structure ported to int8: 128x128 tile, BK=64, 4 waves 2x2,
// 4x4 grid of mfma_i32_16x16x64_i8 per wave. Same 16B-chunk staging,
// same barrier pair, 64 K-iters (half of bf16's 128).
// ============================================================
__global__ void __launch_bounds__(256) gemm_i8_bt(
    const i8* __restrict__ A, const i8* __restrict__ B,
    const float* __restrict__ s, const float* __restrict__ bias,
    float* __restrict__ C, int M, int N, int K)
{
    __shared__ i8 As[BM * BK];   // 8 KB  [128][64] row-major, no padding
    __shared__ i8 Bs[BN * BK];   // 8 KB

    const int t    = threadIdx.x;
    const int lane = t & 63;
    const int wave = t >> 6;
    const int wm   = (wave & 1) * 64;
    const int wn   = (wave >> 1) * 64;
    const int l15  = lane & 15;
    const int quad = lane >> 4;

    // XCD-aware block decode (bid%8 = XCD), 16x16 patch per XCD
    const int nbm = M / BM, nbn = N / BN;
    int mb, nb;
    const int bid = blockIdx.x;
    if (nbm == 64 && nbn == 32) {
        const int xcd    = bid & 7;
        const int local  = bid >> 3;
        const int sub    = local >> 6;
        const int within = local & 63;
        mb = ((xcd >> 1) << 4) + ((sub >> 1) << 3) + (within >> 3);
        nb = ((xcd & 1) << 4) + ((sub & 1) << 3) + (within & 7);
    } else {
        mb = bid / nbn;
        nb = bid - mb * nbn;
    }
    const int m_block = mb * BM;
    const int n_block = nb * BN;

    i32x4 acc[4][4];
#pragma unroll
    for (int i = 0; i < 4; ++i)
#pragma unroll
        for (int j = 0; j < 4; ++j)
            acc[i][j] = (i32x4){0, 0, 0, 0};

    // staging: 8KB tile = 512 x 16B chunks; 4 chunks per 64B row.
    // thread t covers chunks t and t+256.
    const int li0 = t,       ar0 = li0 >> 2, ak0 = (li0 & 3) * 16;
    const int li1 = t + 256, ar1 = li1 >> 2, ak1 = (li1 & 3) * 16;

    const i8* Abase = A + (size_t)m_block * K;
    const i8* Bbase = B + (size_t)n_block * K;

    for (int kt = 0; kt < K; kt += BK) {
        __syncthreads();
        async_cp16(Abase + (size_t)ar0 * K + kt + ak0, &As[li0 * 16]);
        async_cp16(Abase + (size_t)ar1 * K + kt + ak1, &As[li1 * 16]);
        async_cp16(Bbase + (size_t)ar0 * K + kt + ak0, &Bs[li0 * 16]);
        async_cp16(Bbase + (size_t)ar1 * K + kt + ak1, &Bs[li1 * 16]);
        __syncthreads();

        // A fragment: A[m = l15][k = quad*16 + j]  (2xK analog of bf16 quad*8+j)
        i32x4 af[4], bg[4];
#pragma unroll
        for (int i = 0; i < 4; ++i) {
            af[i] = *(const i32x4*)&As[(wm + i * 16 + l15) * BK + quad * 16];
            bg[i] = *(const i32x4*)&Bs[(wn + i * 16 + l15) * BK + quad * 16];
        }
#pragma unroll
        for (int i = 0; i < 4; ++i)
#pragma unroll
            for (int j = 0; j < 4; ++j)
                acc[i][j] = __builtin_amdgcn_mfma_i32_16x16x64_i8(af[i], bg[j], acc[i][j], 0, 0, 0);
    }

    // epilogue: C/D layout col=lane&15, row=quad*4+reg (dtype-independent).
    // out = i32 * s[row] + bias[col]; NT stores (write-once 135MB).
    float bv[4];
#pragma unroll
    for (int j = 0; j < 4; ++j)
        bv[j] = bias[n_block + wn + j * 16 + l15];

#pragma unroll
    for (int i = 0; i < 4; ++i) {
        const int row0 = m_block + wm + i * 16 + quad * 4;  // 4-aligned
        const f4v sv = *(const f4v*)&s[row0];
#pragma unroll
        for (int j = 0; j < 4; ++j) {
            const int col = n_block + wn + j * 16 + l15;
            __builtin_nontemporal_store((float)acc[i][j][0] * sv.x + bv[j], &C[(size_t)(row0 + 0) * N + col]);
            __builtin_nontemporal_store((float)acc[i][j][1] * sv.y + bv[j], &C[(size_t)(row0 + 1) * N + col]);
            __builtin_nontemporal_store((float)acc[i][j][2] * sv.z + bv[j], &C[(size_t)(row0 + 2) * N + col]);
            __builtin_nontemporal_store((float)acc[i][j][3] * sv.w + bv[j], &C[(size_t)(row0 + 3) * N + col]);
        }
    }
}

extern "C" void kernel_launch(void* const* d_in, const int* in_sizes, int n_in,
                              void* d_out, int out_size, void* d_ws, size_t ws_size,
                              hipStream_t stream) {
    const float* x  = (const float*)d_in[0];   // [M,K]
    const float* w  = (const float*)d_in[1];   // [N,K]
    const float* bs = (const float*)d_in[2];   // [N]
    float* out = (float*)d_out;                // [M,N]

    const int N = in_sizes[2];
    const int K = in_sizes[1] / N;
    const int M = in_sizes[0] / K;

    i8*    xq = (i8*)d_ws;                          // [M,K] int8
    i8*    wq = xq + (size_t)M * K;                 // [N,K] int8 (+-1)
    float* s  = (float*)(wq + (size_t)N * K);       // [M] fp32 row scales

    const int xblocks = M;                               // one block per row
    const int wblocks = (int)(((size_t)N * K) / (256 * 16));
    quant_fused<<<xblocks + wblocks, 256, 0, stream>>>(
        (const f4v*)x, (const f4v*)w, xq, wq, s, K, xblocks);

    const int nblocks = (M / BM) * (N / BN);   // 2048
    gemm_i8_bt<<<nblocks, 256, 0, stream>>>(xq, wq, s, bs, out, M, N, K);
}

// Round 4
// 409.893 us; speedup vs baseline: 1.4800x; 1.0504x over previous
//
#include <hip/hip_runtime.h>

typedef unsigned short u16;
typedef unsigned int   u32;
typedef signed char    i8;

#define BM 128
#define BN 128
#define BK 128

typedef __attribute__((ext_vector_type(4))) int   i32x4;
typedef __attribute__((ext_vector_type(4))) float f4v;
typedef __attribute__((ext_vector_type(4))) u32   u4v;

// ============================================================
// Fused quantizer, one dispatch:
//   blocks [0, xblocks)      : per-row int8 quantization of x, scale = absmax/127
//   blocks [xblocks, total)  : sign(w) -> int8 in {-1,0,+1}
// ============================================================
__global__ void __launch_bounds__(256) quant_fused(
    const f4v* __restrict__ x, const f4v* __restrict__ w,
    i8* __restrict__ xq, i8* __restrict__ wq, float* __restrict__ s,
    int K, int xblocks)
{
    const int t    = threadIdx.x;
    const int lane = t & 63;
    const int wave = t >> 6;

    if ((int)blockIdx.x < xblocks) {
        const int row = blockIdx.x;
        const f4v* xr = x + (size_t)row * (K >> 2);
        f4v v[4];
        float amax = 0.f;
#pragma unroll
        for (int c = 0; c < 4; ++c) {
            v[c] = __builtin_nontemporal_load(&xr[t + c * 256]);
            amax = fmaxf(amax, fmaxf(fmaxf(fabsf(v[c].x), fabsf(v[c].y)),
                                     fmaxf(fabsf(v[c].z), fabsf(v[c].w))));
        }
#pragma unroll
        for (int off = 32; off > 0; off >>= 1)
            amax = fmaxf(amax, __shfl_down(amax, off));
        __shared__ float red[4];
        if (lane == 0) red[wave] = amax;
        __syncthreads();
        amax = fmaxf(fmaxf(red[0], red[1]), fmaxf(red[2], red[3]));

        const float inv = (amax > 0.f) ? (127.0f / amax) : 0.f;
        if (t == 0) s[row] = amax * (1.0f / 127.0f);

        i8* xo = xq + (size_t)row * K;
#pragma unroll
        for (int c = 0; c < 4; ++c) {
            const int e = (t + c * 256) * 4;
            int q0 = __float2int_rn(v[c].x * inv);
            int q1 = __float2int_rn(v[c].y * inv);
            int q2 = __float2int_rn(v[c].z * inv);
            int q3 = __float2int_rn(v[c].w * inv);
            u32 p = (q0 & 0xFF) | ((q1 & 0xFF) << 8) |
                    ((q2 & 0xFF) << 16) | ((u32)(q3 & 0xFF) << 24);
            *(u32*)&xo[e] = p;
        }
    } else {
        const int b = blockIdx.x - xblocks;
        const size_t e0 = ((size_t)b * 256 + t) * 16;
        const f4v* wp = w + (e0 >> 2);
        u32 pk[4];
#pragma unroll
        for (int c = 0; c < 4; ++c) {
            f4v a = __builtin_nontemporal_load(&wp[c]);
            u32 b0 = (a.x > 0.f) ? 1u : ((a.x < 0.f) ? 0xFFu : 0u);
            u32 b1 = (a.y > 0.f) ? 1u : ((a.y < 0.f) ? 0xFFu : 0u);
            u32 b2 = (a.z > 0.f) ? 1u : ((a.z < 0.f) ? 0xFFu : 0u);
            u32 b3 = (a.w > 0.f) ? 1u : ((a.w < 0.f) ? 0xFFu : 0u);
            pk[c] = b0 | (b1 << 8) | (b2 << 16) | (b3 << 24);
        }
        u4v r; r.x = pk[0]; r.y = pk[1]; r.z = pk[2]; r.w = pk[3];
        *(u4v*)&wq[e0] = r;
    }
}

// async 16B global -> LDS (LDS dest is wave-uniform base + lane*16)
__device__ __forceinline__ void async_cp16(const void* gp, void* lp) {
    __builtin_amdgcn_global_load_lds(
        (__attribute__((address_space(1))) void*)(gp),
        (__attribute__((address_space(3))) void*)(lp),
        16, 0, 0);
}

// ============================================================
// C[M,N] = (xq . wq^T) * s[row] + bias[col]  -- i8 MFMA, i32 acc
// BK=128 (32KB LDS, 32 barriers instead of 64) + XOR bank swizzle.
//
// Swizzle: LDS tile row = 128B = 8 x 16B chunks. Chunk q of row r is
// stored at LDS chunk position q ^ (r&7). Staging realizes this by lane
// permutation on the GLOBAL side (global_load_lds forces LDS chunk =
// base+lane*16, but vaddr is per-lane). Readers XOR the same way:
// fragment (row r, chunk h*4+quad) -> LDS chunk r*8 + ((h*4+quad)^(r&7)).
// Bank group per lane = ((h*4+quad)^(l15&7))*4 -> 8 distinct groups per
// quad -> 2-way aliasing (free, m136) instead of 16-way.
// ============================================================
__global__ void __launch_bounds__(256) gemm_i8_bt(
    const i8* __restrict__ A, const i8* __restrict__ B,
    const float* __restrict__ s, const float* __restrict__ bias,
    float* __restrict__ C, int M, int N, int K)
{
    __shared__ i8 As[BM * BK];   // 16 KB
    __shared__ i8 Bs[BN * BK];   // 16 KB

    const int t    = threadIdx.x;
    const int lane = t & 63;
    const int wave = t >> 6;
    const int wm   = (wave & 1) * 64;
    const int wn   = (wave >> 1) * 64;
    const int l15  = lane & 15;
    const int quad = lane >> 4;
    const int sw   = l15 & 7;          // reader swizzle key (row&7)

    // XCD-aware block decode (bid%8 = XCD), 16x16 patch per XCD
    const int nbm = M / BM, nbn = N / BN;
    int mb, nb;
    const int bid = blockIdx.x;
    if (nbm == 64 && nbn == 32) {
        const int xcd    = bid & 7;
        const int local  = bid >> 3;
        const int sub    = local >> 6;
        const int within = local & 63;
        mb = ((xcd >> 1) << 4) + ((sub >> 1) << 3) + (within >> 3);
        nb = ((xcd & 1) << 4) + ((sub & 1) << 3) + (within & 7);
    } else {
        mb = bid / nbn;
        nb = bid - mb * nbn;
    }
    const int m_block = mb * BM;
    const int n_block = nb * BN;

    i32x4 acc[4][4];
#pragma unroll
    for (int i = 0; i < 4; ++i)
#pragma unroll
        for (int j = 0; j < 4; ++j)
            acc[i][j] = (i32x4){0, 0, 0, 0};

    // staging: 16KB tile = 1024 x 16B chunks; thread t covers c = t + k*256.
    // LDS chunk c <- global chunk (row = c>>3, gq = (c&7) ^ (row&7)).
    const i8* Abase = A + (size_t)m_block * K;
    const i8* Bbase = B + (size_t)n_block * K;
    const i8* ga[4]; const i8* gb[4]; int lc[4];
#pragma unroll
    for (int k = 0; k < 4; ++k) {
        const int c  = t + k * 256;
        const int r  = c >> 3;
        const int gq = (c & 7) ^ (r & 7);
        lc[k] = c * 16;
        ga[k] = Abase + (size_t)r * K + gq * 16;
        gb[k] = Bbase + (size_t)r * K + gq * 16;
    }

    for (int kt = 0; kt < K; kt += BK) {
        __syncthreads();
#pragma unroll
        for (int k = 0; k < 4; ++k) async_cp16(ga[k] + kt, &As[lc[k]]);
#pragma unroll
        for (int k = 0; k < 4; ++k) async_cp16(gb[k] + kt, &Bs[lc[k]]);
        __syncthreads();

#pragma unroll
        for (int h = 0; h < 2; ++h) {
            // fragment (row, k = h*64 + quad*16 + j): LDS chunk row*8 + ((h*4+quad)^sw)
            const int cq = ((h * 4 + quad) ^ sw) * 16;
            i32x4 af[4], bg[4];
#pragma unroll
            for (int i = 0; i < 4; ++i) {
                af[i] = *(const i32x4*)&As[(wm + i * 16 + l15) * BK + cq];
                bg[i] = *(const i32x4*)&Bs[(wn + i * 16 + l15) * BK + cq];
            }
#pragma unroll
            for (int i = 0; i < 4; ++i)
#pragma unroll
                for (int j = 0; j < 4; ++j)
                    acc[i][j] = __builtin_amdgcn_mfma_i32_16x16x64_i8(af[i], bg[j], acc[i][j], 0, 0, 0);
        }
    }

    // epilogue: C/D layout col=lane&15, row=quad*4+reg (dtype-independent)
    float bv[4];
#pragma unroll
    for (int j = 0; j < 4; ++j)
        bv[j] = bias[n_block + wn + j * 16 + l15];

#pragma unroll
    for (int i = 0; i < 4; ++i) {
        const int row0 = m_block + wm + i * 16 + quad * 4;
        const f4v sv = *(const f4v*)&s[row0];
#pragma unroll
        for (int j = 0; j < 4; ++j) {
            const int col = n_block + wn + j * 16 + l15;
            __builtin_nontemporal_store((float)acc[i][j][0] * sv.x + bv[j], &C[(size_t)(row0 + 0) * N + col]);
            __builtin_nontemporal_store((float)acc[i][j][1] * sv.y + bv[j], &C[(size_t)(row0 + 1) * N + col]);
            __builtin_nontemporal_store((float)acc[i][j][2] * sv.z + bv[j], &C[(size_t)(row0 + 2) * N + col]);
            __builtin_nontemporal_store((float)acc[i][j][3] * sv.w + bv[j], &C[(size_t)(row0 + 3) * N + col]);
        }
    }
}

extern "C" void kernel_launch(void* const* d_in, const int* in_sizes, int n_in,
                              void* d_out, int out_size, void* d_ws, size_t ws_size,
                              hipStream_t stream) {
    const float* x  = (const float*)d_in[0];   // [M,K]
    const float* w  = (const float*)d_in[1];   // [N,K]
    const float* bs = (const float*)d_in[2];   // [N]
    float* out = (float*)d_out;                // [M,N]

    const int N = in_sizes[2];
    const int K = in_sizes[1] / N;
    const int M = in_sizes[0] / K;

    i8*    xq = (i8*)d_ws;                          // [M,K] int8
    i8*    wq = xq + (size_t)M * K;                 // [N,K] int8 (+-1)
    float* s  = (float*)(wq + (size_t)N * K);       // [M] fp32 row scales

    const int xblocks = M;
    const int wblocks = (int)(((size_t)N * K) / (256 * 16));
    quant_fused<<<xblocks + wblocks, 256, 0, stream>>>(
        (const f4v*)x, (const f4v*)w, xq, wq, s, K, xblocks);

    const int nblocks = (M / BM) * (N / BN);   // 2048
    gemm_i8_bt<<<nblocks, 256, 0, stream>>>(xq, wq, s, bs, out, M, N, K);
}